// Round 8
// baseline (255.853 us; speedup 1.0000x reference)
//
#include <hip/hip_runtime.h>
#include <stdint.h>

typedef unsigned short u16;
typedef __attribute__((ext_vector_type(4))) short short4v;
typedef __attribute__((ext_vector_type(8))) short short8;
typedef __attribute__((ext_vector_type(4))) float floatx4;
typedef __attribute__((ext_vector_type(4))) unsigned short u16x4;

typedef __attribute__((address_space(1))) const void* gas_ptr;
typedef __attribute__((address_space(3))) void* las_ptr;

__device__ __forceinline__ void async16(const void* g, void* l) {
    __builtin_amdgcn_global_load_lds((gas_ptr)g, (las_ptr)l, 16, 0, 0);
}

__device__ __forceinline__ u16 f2bf(float f) {
    union { float f; unsigned int u; } v; v.f = f;
    unsigned int r = v.u + 0x7fffu + ((v.u >> 16) & 1u);
    return (u16)(r >> 16);
}

__device__ __forceinline__ int pk_bf16(float a, float b) {
    return (int)((unsigned int)f2bf(a) | ((unsigned int)f2bf(b) << 16));
}

// truncation pack: high halves of {b,a}, b in high 16. P feeds BOTH the PV
// numerator and the ones-MFMA denominator, so the truncation bias is
// common-mode and cancels in the softmax ratio. 1 VALU op vs 3.
// (v_cvt_pk_bf16_f32 asm FAILED numerics in r1 — do not reintroduce.)
__device__ __forceinline__ int pk2t(float a, float b) {
    union { float f; unsigned int u; } ua, ub;
    ua.f = a; ub.f = b;
    return (int)__builtin_amdgcn_perm(ub.u, ua.u, 0x07060302u);
}

// ---------------- converts ----------------
__global__ void cvt_w_kernel(const float* __restrict__ src, u16* __restrict__ dst) {
    int i = blockIdx.x * 256 + threadIdx.x;
    float4 f = reinterpret_cast<const float4*>(src)[i];
    u16x4 o;
    o.x = f2bf(f.x); o.y = f2bf(f.y); o.z = f2bf(f.z); o.w = f2bf(f.w);
    reinterpret_cast<u16x4*>(dst)[i] = o;
}

__global__ void cvt_x_kernel(const float* __restrict__ x, u16* __restrict__ xb,
                             u16* __restrict__ xout) {
    int i = blockIdx.x * 256 + threadIdx.x;
    float4 f = reinterpret_cast<const float4*>(x)[i];
    u16x4 o;
    o.x = f2bf(f.x); o.y = f2bf(f.y); o.z = f2bf(f.z); o.w = f2bf(f.w);
    reinterpret_cast<u16x4*>(xb)[i] = o;
    int m = (i * 4) >> 10;
    if ((m & 2047) < 256) reinterpret_cast<u16x4*>(xout)[i] = o;
}

// ---------------- QKV GEMM: 256x192 block, 8 waves (2Mx4N), wave 128x48 ----
// r7 falsified load-latency theory (counted vmcnt + dist-2 = neutral at 128²);
// r4/r5/r7 triangulate to LDS-PORT saturation: 128² moves ~20KB/K-step/CU
// through the 256B/cyc port (stage 16KB + frags 4KB) ≈ the MFMA time itself.
// This geometry cuts stage-write bytes/MFMA 4x (256-row tile) and read
// bytes/MFMA 25% (128-row wave tile) -> LDS ~154cyc vs MFMA ~233cyc per tile.
// BN=192 so grid = 32x16 = 512 blocks = exactly 2 rounds at 1 block/CU.
// 3 LDS bufs (84KB), dist-2 prefetch, vmcnt(4) boundary (4 stage-ops/thread/
// tile, made wave-uniform via benign B double-write), 2 lockstep phases/tile
// with setprio(1) MFMA clusters (role-split scheduling, T3-lite+T5).
// Outputs: Q (pre-scaled 0.125*log2e) [bh][n][64], K [bh][n][64],
//          Vf lane-tiled: Vf[bh][key>>5][d>>4][((key>>3)&3)*16+(d&15)][key&7]
__global__ void __launch_bounds__(512, 2)
gemm_qkv(const u16* __restrict__ A, const u16* __restrict__ B,
         u16* __restrict__ q_out, u16* __restrict__ k_out, u16* __restrict__ vt_out) {
    __shared__ u16 As[3][256 * 32];
    __shared__ u16 Bs[3][192 * 32];
    const int tid  = threadIdx.x;
    const int lane = tid & 63;
    const int w    = tid >> 6;
    const int wr   = w >> 2;        // 0..1
    const int wc   = w & 3;         // 0..3
    const int row0 = blockIdx.x * 256;
    const int col0 = blockIdx.y * 192;
    const int m    = lane & 15;
    const int g    = lane >> 4;

    floatx4 acc[8][3] = {};

// A tile: 1024 slots of 16B; slot p: row r=p>>2, chunk-pos = chunk ^ ((r>>1)&3)
#define STAGE_A8(buf, kelem)                                                    \
    do {                                                                        \
        _Pragma("unroll")                                                       \
        for (int i = 0; i < 2; ++i) {                                           \
            int p = tid + i * 512;                                              \
            int r = p >> 2;                                                     \
            int c = (p & 3) ^ ((r >> 1) & 3);                                   \
            async16(A + (size_t)(row0 + r) * 1024 + ((kelem) + c * 8),          \
                    (char*)&As[buf][0] + p * 16);                               \
        }                                                                       \
    } while (0)

// B tile: 768 slots; every thread does exactly 2 ops (slots 256..511 written
// twice with identical data -> benign; keeps vmcnt wave-uniform at 4/tile)
#define STAGE_B8(buf, kelem)                                                    \
    do {                                                                        \
        _Pragma("unroll")                                                       \
        for (int i = 0; i < 2; ++i) {                                           \
            int p = (i == 0) ? tid : (tid + 256);                               \
            int r = p >> 2;                                                     \
            int c = (p & 3) ^ ((r >> 1) & 3);                                   \
            async16(B + (size_t)(col0 + r) * 1024 + ((kelem) + c * 8),          \
                    (char*)&Bs[buf][0] + p * 16);                               \
        }                                                                       \
    } while (0)

    STAGE_A8(0, 0);  STAGE_B8(0, 0);
    STAGE_A8(1, 32); STAGE_B8(1, 32);

    int cur = 0, nx2 = 2;
    for (int kt = 0; kt < 32; ++kt) {
        if (kt < 31) asm volatile("s_waitcnt vmcnt(4)" ::: "memory");
        else         asm volatile("s_waitcnt vmcnt(0)" ::: "memory");
        __builtin_amdgcn_s_barrier();

        const u16* as = &As[cur][0];
        const u16* bs = &Bs[cur][0];
        short8 af[8], bf[3];
        // ---- phase 1: B frags + A frags 0-3, stage A(kt+2), MFMA quad 1 ----
#pragma unroll
        for (int j = 0; j < 3; ++j) {
            int br = wc * 48 + j * 16 + m;
            bf[j] = *(const short8*)(bs + br * 32 + (g ^ ((br >> 1) & 3)) * 8);
        }
#pragma unroll
        for (int i = 0; i < 4; ++i) {
            int ar = wr * 128 + i * 16 + m;
            af[i] = *(const short8*)(as + ar * 32 + (g ^ ((ar >> 1) & 3)) * 8);
        }
        if (kt + 2 < 32) STAGE_A8(nx2, (kt + 2) * 32);
        __builtin_amdgcn_s_setprio(1);
#pragma unroll
        for (int i = 0; i < 4; ++i)
#pragma unroll
            for (int j = 0; j < 3; ++j)
                acc[i][j] = __builtin_amdgcn_mfma_f32_16x16x32_bf16(af[i], bf[j], acc[i][j], 0, 0, 0);
        __builtin_amdgcn_s_setprio(0);
        __builtin_amdgcn_s_barrier();
        // ---- phase 2: A frags 4-7, stage B(kt+2), MFMA quad 2 ----
#pragma unroll
        for (int i = 4; i < 8; ++i) {
            int ar = wr * 128 + i * 16 + m;
            af[i] = *(const short8*)(as + ar * 32 + (g ^ ((ar >> 1) & 3)) * 8);
        }
        if (kt + 2 < 32) STAGE_B8(nx2, (kt + 2) * 32);
        __builtin_amdgcn_s_setprio(1);
#pragma unroll
        for (int i = 4; i < 8; ++i)
#pragma unroll
            for (int j = 0; j < 3; ++j)
                acc[i][j] = __builtin_amdgcn_mfma_f32_16x16x32_bf16(af[i], bf[j], acc[i][j], 0, 0, 0);
        __builtin_amdgcn_s_setprio(0);

        cur = (cur == 2) ? 0 : cur + 1;
        nx2 = (nx2 == 2) ? 0 : nx2 + 1;
    }
#undef STAGE_A8
#undef STAGE_B8

#pragma unroll
    for (int i = 0; i < 8; ++i) {
#pragma unroll
        for (int j = 0; j < 3; ++j) {
            int gr0 = row0 + wr * 128 + i * 16 + (g << 2);
            int gc  = col0 + wc * 48 + j * 16 + m;
            int which = gc >> 10;
            int cl = gc & 1023;
            int h = cl >> 6, d = cl & 63;
            int b = gr0 >> 11, n0 = gr0 & 2047;
            int bh = b * 16 + h;
            if (which == 2) {
                // keys n0..n0+3 live in one 8-key group: j = (n0&4)+r
                u16x4 pk;
                pk.x = f2bf(acc[i][j][0]); pk.y = f2bf(acc[i][j][1]);
                pk.z = f2bf(acc[i][j][2]); pk.w = f2bf(acc[i][j][3]);
                size_t off = (size_t)bh * 131072
                           + (((size_t)(n0 >> 5) * 4 + (d >> 4)) * 64
                              + ((n0 >> 3) & 3) * 16 + (d & 15)) * 8 + (n0 & 4);
                *reinterpret_cast<u16x4*>(vt_out + off) = pk;
            } else {
                u16* dst = (which == 0) ? q_out : k_out;
                float sc = (which == 0) ? 0.18033688f : 1.0f;  // 0.125*log2(e)
#pragma unroll
                for (int r = 0; r < 4; ++r)
                    dst[((size_t)bh * 2048 + n0 + r) * 64 + d] = f2bf(acc[i][j][r] * sc);
            }
        }
    }
}

// ---------------- NT GEMM (proj): 128x128 block, r7 version (proven) -------
template<int MODE>
__global__ void __launch_bounds__(256, 2)
gemm_nt(const u16* __restrict__ A, const u16* __restrict__ B,
        float* __restrict__ f_out, const float* __restrict__ bias, int K) {
    __shared__ u16 As[3][128 * 32];
    __shared__ u16 Bs[3][128 * 32];
    const int tid  = threadIdx.x;
    const int lane = tid & 63;
    const int w    = tid >> 6;
    const int row0 = blockIdx.x * 128;
    const int col0 = blockIdx.y * 128;
    const int wm   = (w >> 1) * 64;
    const int wn   = (w & 1) * 64;

    floatx4 acc[4][4] = {};

#define STAGE_G(buf, kelem)                                                     \
    do {                                                                        \
        _Pragma("unroll")                                                       \
        for (int i = 0; i < 2; ++i) {                                           \
            int pb = w * 128 + i * 64;                                          \
            int p  = pb + lane;                                                 \
            int r  = p >> 2;                                                    \
            int c  = (p & 3) ^ ((r >> 1) & 3);                                  \
            async16(A + (size_t)(row0 + r) * K + ((kelem) + c * 8),             \
                    (char*)&As[buf][0] + p * 16);                               \
            async16(B + (size_t)(col0 + r) * K + ((kelem) + c * 8),             \
                    (char*)&Bs[buf][0] + p * 16);                               \
        }                                                                       \
    } while (0)

    STAGE_G(0, 0);
    STAGE_G(1, 32);
    const int nk = K >> 5;

    int cur = 0;
    int nx2 = 2;
    for (int kt = 0; kt < nk; ++kt) {
        if (kt + 1 < nk) {
            asm volatile("s_waitcnt vmcnt(4)" ::: "memory");
        } else {
            asm volatile("s_waitcnt vmcnt(0)" ::: "memory");
        }
        __builtin_amdgcn_s_barrier();
        __builtin_amdgcn_sched_barrier(0);
        if (kt + 2 < nk) STAGE_G(nx2, (kt + 2) << 5);

        const u16* as = &As[cur][0];
        const u16* bs = &Bs[cur][0];
        short8 af[4], bf_[4];
#pragma unroll
        for (int t = 0; t < 4; ++t) {
            int ar = wm + t * 16 + (lane & 15);
            int ca = (lane >> 4) ^ ((ar >> 1) & 3);
            af[t]  = *(const short8*)(as + ar * 32 + ca * 8);
            int br = wn + t * 16 + (lane & 15);
            int cb = (lane >> 4) ^ ((br >> 1) & 3);
            bf_[t] = *(const short8*)(bs + br * 32 + cb * 8);
        }
#pragma unroll
        for (int i = 0; i < 4; ++i)
#pragma unroll
            for (int j = 0; j < 4; ++j)
                acc[i][j] = __builtin_amdgcn_mfma_f32_16x16x32_bf16(af[i], bf_[j], acc[i][j], 0, 0, 0);

        cur = (cur == 2) ? 0 : cur + 1;
        nx2 = (nx2 == 2) ? 0 : nx2 + 1;
    }
#undef STAGE_G

#pragma unroll
    for (int i = 0; i < 4; ++i) {
#pragma unroll
        for (int j = 0; j < 4; ++j) {
            int gr0 = row0 + wm + i * 16 + ((lane >> 4) << 2);
            int gc  = col0 + wn + j * 16 + (lane & 15);
            float bv = bias[gc];
#pragma unroll
            for (int r = 0; r < 4; ++r)
                f_out[(size_t)(gr0 + r) * 1024 + gc] = acc[i][j][r] + bv;
        }
    }
}

// ---------------- flash attention: 32 queries/wave, fixed-max softmax -------
// 1-D grid 896: bh = id&63 (XCD-local K/V), qt = id>>6 (14 tiles of 128 q).
// block 256 = 4 waves; wave owns 32 queries as two 16-query B-frag sets.
// V staged through LDS like K (r6: removed 4x redundant per-wave L2 reads).
// QK A-operand rows key-permuted so S^T regs land in 16x16x32 B-frag layout;
// PV at K=32 straight from registers; lsum via ones-MFMA; truncation pack;
// s_setprio(1) around MFMA clusters (T5).
__global__ void __launch_bounds__(256, 3)
flash_attn(const u16* __restrict__ Qg, const u16* __restrict__ Kg,
           const u16* __restrict__ Vf, u16* __restrict__ xout) {
    __shared__ u16 Ks[2][64 * 64];
    __shared__ u16 Vs[2][8 * 512];
    const int lane = threadIdx.x & 63;
    const int w    = threadIdx.x >> 6;
    const int bh   = blockIdx.x & 63;
    const int qt   = blockIdx.x >> 6;
    const int q0   = 256 + qt * 128 + w * 32;
    const size_t kvbase = (size_t)bh * 2048 * 64;

    const int m = lane & 15;
    const int g = lane >> 4;

    // Q frags (B-operand of 16x16x32): query q0+qs*16+m, k=g*8+j
    short8 qf[2][2];
#pragma unroll
    for (int qs = 0; qs < 2; ++qs) {
        const u16* p = Qg + kvbase + (size_t)(q0 + qs * 16 + m) * 64 + g * 8;
        qf[qs][0] = *(const short8*)(p);
        qf[qs][1] = *(const short8*)(p + 32);
    }

    // V global base: frag-group j = b32*4+i of tile kt lives at
    // vg + (kt*8 + j)*512 + lane*8  (contiguous 1KB per group)
    const u16* vg = Vf + (size_t)bh * 131072;

    // K staging: slot p holds row r=p>>3, chunk-pos p&7 = data chunk ^ f(r),
    // f(r) = ((r>>3)&1)*4 + (r&3)
    const int p0 = w * 64 + lane;
    const int tid = threadIdx.x;
#define STAGE_KV(buf, kt)                                                       \
    {                                                                           \
        _Pragma("unroll")                                                       \
        for (int i = 0; i < 2; ++i) {                                           \
            int p = i * 256 + p0;                                               \
            int r = p >> 3;                                                     \
            int c = (p & 7) ^ ((((r >> 3) & 1) << 2) | (r & 3));                \
            async16(Kg + kvbase + (size_t)((kt) * 64 + r) * 64 + c * 8,         \
                    (char*)&Ks[buf][0] + p * 16);                               \
        }                                                                       \
        _Pragma("unroll")                                                       \
        for (int i = 0; i < 2; ++i) {                                           \
            int p = i * 256 + tid;                                              \
            async16(vg + (size_t)((kt) * 8 + (p >> 6)) * 512 + (p & 63) * 8,    \
                    (char*)&Vs[buf][0] + p * 16);                               \
        }                                                                       \
    }

    STAGE_KV(0, 0);

    // hoisted constants: QK acc init quad (MFMA C-operand, read-only) and
    // all-ones bf16 A-frag for the lsum MFMA
    const floatx4 ZROW = {-32.f, -32.f, -32.f, -32.f};
    short8 ones1;
#pragma unroll
    for (int i = 0; i < 8; ++i) ones1[i] = (short)0x3F80;

    floatx4 lacc[2] = {};
    floatx4 o[2][4] = {};

    const int fm = ((m >> 2) & 1) * 4 + (m & 3);   // = f(r) for this lane's rows

    for (int kt = 0; kt < 32; ++kt) {
        __syncthreads();
        if (kt + 1 < 32) STAGE_KV((kt + 1) & 1, kt + 1);

        const u16* kbuf = &Ks[kt & 1][0];
        const u16* vbuf = &Vs[kt & 1][0];
#pragma unroll
        for (int b32 = 0; b32 < 2; ++b32) {
            // V A-frags for this 32-key block, from LDS (1KB contiguous/frag)
            short8 vfr[4];
#pragma unroll
            for (int i = 0; i < 4; ++i)
                vfr[i] = *(const short8*)(vbuf + ((b32 * 4 + i) * 64 + lane) * 8);

            // S^T tiles: A row = key b32*32 + (m>>2)*8 + t*4 + (m&3)
            floatx4 sT[2][2];
#pragma unroll
            for (int t = 0; t < 2; ++t) {
                int r = b32 * 32 + (m >> 2) * 8 + t * 4 + (m & 3);
                short8 k0 = *(const short8*)(kbuf + r * 64 + ((g)     ^ fm) * 8);
                short8 k1 = *(const short8*)(kbuf + r * 64 + ((4 + g) ^ fm) * 8);
                __builtin_amdgcn_s_setprio(1);
#pragma unroll
                for (int qs = 0; qs < 2; ++qs) {
                    floatx4 z = __builtin_amdgcn_mfma_f32_16x16x32_bf16(k0, qf[qs][0], ZROW, 0, 0, 0);
                    sT[qs][t] = __builtin_amdgcn_mfma_f32_16x16x32_bf16(k1, qf[qs][1], z, 0, 0, 0);
                }
                __builtin_amdgcn_s_setprio(0);
            }

            // exp2, pack P^T (16x16x32 B-frag: j -> key g*8+j), PV at K=32
#pragma unroll
            for (int qs = 0; qs < 2; ++qs) {
                float p[8];
#pragma unroll
                for (int t = 0; t < 2; ++t)
#pragma unroll
                    for (int r = 0; r < 4; ++r)
                        p[t * 4 + r] = __builtin_amdgcn_exp2f(sT[qs][t][r]);
                union { int i4[4]; short8 s8; } u;
                u.i4[0] = pk2t(p[0], p[1]);
                u.i4[1] = pk2t(p[2], p[3]);
                u.i4[2] = pk2t(p[4], p[5]);
                u.i4[3] = pk2t(p[6], p[7]);
                __builtin_amdgcn_s_setprio(1);
#pragma unroll
                for (int i = 0; i < 4; ++i)
                    o[qs][i] = __builtin_amdgcn_mfma_f32_16x16x32_bf16(vfr[i], u.s8, o[qs][i], 0, 0, 0);
                // row-sum of P via ones-MFMA: lacc[qs][*] = sum_k P[q][k]
                lacc[qs] = __builtin_amdgcn_mfma_f32_16x16x32_bf16(ones1, u.s8, lacc[qs], 0, 0, 0);
                __builtin_amdgcn_s_setprio(0);
            }
        }
    }

    const int b = bh >> 4, h = bh & 15;
#pragma unroll
    for (int qs = 0; qs < 2; ++qs) {
        // every lane already holds the full row sum for its query (col=lane&15)
        const float inv = 1.f / lacc[qs][0];

        // epilogue: O^T C-layout: col=q=m, row=d=i*16+g*4+r
        const int n = q0 + qs * 16 + m;
        u16* dst = xout + (size_t)(b * 2048 + n) * 1024 + h * 64 + (g << 2);
#pragma unroll
        for (int i = 0; i < 4; ++i) {
            union { int i2[2]; u16x4 s4; } u;
            u.i2[0] = pk_bf16(o[qs][i][0] * inv, o[qs][i][1] * inv);
            u.i2[1] = pk_bf16(o[qs][i][2] * inv, o[qs][i][3] * inv);
            *reinterpret_cast<u16x4*>(dst + i * 16) = u.s4;
        }
    }
#undef STAGE_KV
}

// ---------------- launch ----------------
extern "C" void kernel_launch(void* const* d_in, const int* in_sizes, int n_in,
                              void* d_out, int out_size, void* d_ws, size_t ws_size,
                              hipStream_t stream) {
    const float* x      = (const float*)d_in[0];
    const float* qkv_w  = (const float*)d_in[1];
    const float* proj_w = (const float*)d_in[2];
    const float* proj_b = (const float*)d_in[3];

    char* ws = (char*)d_ws;
    u16* xb    = (u16*)(ws);                       // 16 MB
    u16* xout  = (u16*)(ws + ((size_t)16 << 20));  // 16 MB
    u16* wqkv  = (u16*)(ws + ((size_t)32 << 20));  //  6 MB
    u16* wproj = (u16*)(ws + ((size_t)38 << 20));  //  2 MB
    u16* Qb    = (u16*)(ws + ((size_t)40 << 20));  // 16 MB [bh][n][64] (pre-scaled)
    u16* Kb    = (u16*)(ws + ((size_t)56 << 20));  // 16 MB [bh][n][64]
    u16* Vfb   = (u16*)(ws + ((size_t)72 << 20));  // 16 MB lane-tiled for K=32 PV

    cvt_x_kernel<<<8192, 256, 0, stream>>>(x, xb, xout);
    cvt_w_kernel<<<3072, 256, 0, stream>>>(qkv_w, wqkv);
    cvt_w_kernel<<<1024, 256, 0, stream>>>(proj_w, wproj);
    gemm_qkv<<<dim3(32, 16), 512, 0, stream>>>(xb, wqkv, Qb, Kb, Vfb);
    flash_attn<<<896, 256, 0, stream>>>(Qb, Kb, Vfb, xout);
    gemm_nt<1><<<dim3(64, 8), 256, 0, stream>>>(xout, wproj, (float*)d_out, proj_b, 1024);
}

// Round 9
// 247.472 us; speedup vs baseline: 1.0339x; 1.0339x over previous
//
#include <hip/hip_runtime.h>
#include <stdint.h>

typedef unsigned short u16;
typedef __attribute__((ext_vector_type(4))) short short4v;
typedef __attribute__((ext_vector_type(8))) short short8;
typedef __attribute__((ext_vector_type(4))) float floatx4;
typedef __attribute__((ext_vector_type(4))) unsigned short u16x4;

typedef __attribute__((address_space(1))) const void* gas_ptr;
typedef __attribute__((address_space(3))) void* las_ptr;

__device__ __forceinline__ void async16(const void* g, void* l) {
    __builtin_amdgcn_global_load_lds((gas_ptr)g, (las_ptr)l, 16, 0, 0);
}

__device__ __forceinline__ u16 f2bf(float f) {
    union { float f; unsigned int u; } v; v.f = f;
    unsigned int r = v.u + 0x7fffu + ((v.u >> 16) & 1u);
    return (u16)(r >> 16);
}

__device__ __forceinline__ int pk_bf16(float a, float b) {
    return (int)((unsigned int)f2bf(a) | ((unsigned int)f2bf(b) << 16));
}

// truncation pack: high halves of {b,a}, b in high 16. P feeds BOTH the PV
// numerator and the ones-MFMA denominator, so the truncation bias is
// common-mode and cancels in the softmax ratio. 1 VALU op vs 3.
// (v_cvt_pk_bf16_f32 asm FAILED numerics in r1 — do not reintroduce.)
__device__ __forceinline__ int pk2t(float a, float b) {
    union { float f; unsigned int u; } ua, ub;
    ua.f = a; ub.f = b;
    return (int)__builtin_amdgcn_perm(ub.u, ua.u, 0x07060302u);
}

// ---------------- merged converts (one launch instead of three) ------------
// blocks [0,8192): x -> xb (+ first-256-rows copy to xout)
// blocks [8192,11264): qkv_w -> wqkv
// blocks [11264,12288): proj_w -> wproj
__global__ void cvt_all(const float* __restrict__ x, u16* __restrict__ xb,
                        u16* __restrict__ xout,
                        const float* __restrict__ qkv_w, u16* __restrict__ wqkv,
                        const float* __restrict__ proj_w, u16* __restrict__ wproj) {
    int b = blockIdx.x;
    const float* src;
    u16* dst;
    int i;
    if (b < 8192)       { src = x;      dst = xb;    i = b * 256 + threadIdx.x; }
    else if (b < 11264) { src = qkv_w;  dst = wqkv;  i = (b - 8192) * 256 + threadIdx.x; }
    else                { src = proj_w; dst = wproj; i = (b - 11264) * 256 + threadIdx.x; }
    float4 f = reinterpret_cast<const float4*>(src)[i];
    u16x4 o;
    o.x = f2bf(f.x); o.y = f2bf(f.y); o.z = f2bf(f.z); o.w = f2bf(f.w);
    reinterpret_cast<u16x4*>(dst)[i] = o;
    if (b < 8192) {
        int m = (i * 4) >> 10;
        if ((m & 2047) < 256) reinterpret_cast<u16x4*>(xout)[i] = o;
    }
}

// ---------------- QKV GEMM: 256x192 block, 8 waves (2Mx4N), wave 128x48 ----
// (r8 structure, kept verbatim.) LDS-port economics: 4x fewer stage-write
// bytes/MFMA than 128², 3 bufs, dist-2 prefetch, vmcnt(4) boundary,
// 2 lockstep phases/tile with setprio(1) MFMA clusters.
// Outputs: Q (pre-scaled 0.125*log2e) [bh][n][64], K [bh][n][64],
//          Vf lane-tiled: Vf[bh][key>>5][d>>4][((key>>3)&3)*16+(d&15)][key&7]
__global__ void __launch_bounds__(512, 2)
gemm_qkv(const u16* __restrict__ A, const u16* __restrict__ B,
         u16* __restrict__ q_out, u16* __restrict__ k_out, u16* __restrict__ vt_out) {
    __shared__ u16 As[3][256 * 32];
    __shared__ u16 Bs[3][192 * 32];
    const int tid  = threadIdx.x;
    const int lane = tid & 63;
    const int w    = tid >> 6;
    const int wr   = w >> 2;        // 0..1
    const int wc   = w & 3;         // 0..3
    const int row0 = blockIdx.x * 256;
    const int col0 = blockIdx.y * 192;
    const int m    = lane & 15;
    const int g    = lane >> 4;

    floatx4 acc[8][3] = {};

#define STAGE_A8(buf, kelem)                                                    \
    do {                                                                        \
        _Pragma("unroll")                                                       \
        for (int i = 0; i < 2; ++i) {                                           \
            int p = tid + i * 512;                                              \
            int r = p >> 2;                                                     \
            int c = (p & 3) ^ ((r >> 1) & 3);                                   \
            async16(A + (size_t)(row0 + r) * 1024 + ((kelem) + c * 8),          \
                    (char*)&As[buf][0] + p * 16);                               \
        }                                                                       \
    } while (0)

#define STAGE_B8(buf, kelem)                                                    \
    do {                                                                        \
        _Pragma("unroll")                                                       \
        for (int i = 0; i < 2; ++i) {                                           \
            int p = (i == 0) ? tid : (tid + 256);                               \
            int r = p >> 2;                                                     \
            int c = (p & 3) ^ ((r >> 1) & 3);                                   \
            async16(B + (size_t)(col0 + r) * 1024 + ((kelem) + c * 8),          \
                    (char*)&Bs[buf][0] + p * 16);                               \
        }                                                                       \
    } while (0)

    STAGE_A8(0, 0);  STAGE_B8(0, 0);
    STAGE_A8(1, 32); STAGE_B8(1, 32);

    int cur = 0, nx2 = 2;
    for (int kt = 0; kt < 32; ++kt) {
        if (kt < 31) asm volatile("s_waitcnt vmcnt(4)" ::: "memory");
        else         asm volatile("s_waitcnt vmcnt(0)" ::: "memory");
        __builtin_amdgcn_s_barrier();

        const u16* as = &As[cur][0];
        const u16* bs = &Bs[cur][0];
        short8 af[8], bf[3];
        // ---- phase 1: B frags + A frags 0-3, stage A(kt+2), MFMA quad 1 ----
#pragma unroll
        for (int j = 0; j < 3; ++j) {
            int br = wc * 48 + j * 16 + m;
            bf[j] = *(const short8*)(bs + br * 32 + (g ^ ((br >> 1) & 3)) * 8);
        }
#pragma unroll
        for (int i = 0; i < 4; ++i) {
            int ar = wr * 128 + i * 16 + m;
            af[i] = *(const short8*)(as + ar * 32 + (g ^ ((ar >> 1) & 3)) * 8);
        }
        if (kt + 2 < 32) STAGE_A8(nx2, (kt + 2) * 32);
        __builtin_amdgcn_s_setprio(1);
#pragma unroll
        for (int i = 0; i < 4; ++i)
#pragma unroll
            for (int j = 0; j < 3; ++j)
                acc[i][j] = __builtin_amdgcn_mfma_f32_16x16x32_bf16(af[i], bf[j], acc[i][j], 0, 0, 0);
        __builtin_amdgcn_s_setprio(0);
        __builtin_amdgcn_s_barrier();
        // ---- phase 2: A frags 4-7, stage B(kt+2), MFMA quad 2 ----
#pragma unroll
        for (int i = 4; i < 8; ++i) {
            int ar = wr * 128 + i * 16 + m;
            af[i] = *(const short8*)(as + ar * 32 + (g ^ ((ar >> 1) & 3)) * 8);
        }
        if (kt + 2 < 32) STAGE_B8(nx2, (kt + 2) * 32);
        __builtin_amdgcn_s_setprio(1);
#pragma unroll
        for (int i = 4; i < 8; ++i)
#pragma unroll
            for (int j = 0; j < 3; ++j)
                acc[i][j] = __builtin_amdgcn_mfma_f32_16x16x32_bf16(af[i], bf[j], acc[i][j], 0, 0, 0);
        __builtin_amdgcn_s_setprio(0);

        cur = (cur == 2) ? 0 : cur + 1;
        nx2 = (nx2 == 2) ? 0 : nx2 + 1;
    }
#undef STAGE_A8
#undef STAGE_B8

#pragma unroll
    for (int i = 0; i < 8; ++i) {
#pragma unroll
        for (int j = 0; j < 3; ++j) {
            int gr0 = row0 + wr * 128 + i * 16 + (g << 2);
            int gc  = col0 + wc * 48 + j * 16 + m;
            int which = gc >> 10;
            int cl = gc & 1023;
            int h = cl >> 6, d = cl & 63;
            int b = gr0 >> 11, n0 = gr0 & 2047;
            int bh = b * 16 + h;
            if (which == 2) {
                u16x4 pk;
                pk.x = f2bf(acc[i][j][0]); pk.y = f2bf(acc[i][j][1]);
                pk.z = f2bf(acc[i][j][2]); pk.w = f2bf(acc[i][j][3]);
                size_t off = (size_t)bh * 131072
                           + (((size_t)(n0 >> 5) * 4 + (d >> 4)) * 64
                              + ((n0 >> 3) & 3) * 16 + (d & 15)) * 8 + (n0 & 4);
                *reinterpret_cast<u16x4*>(vt_out + off) = pk;
            } else {
                u16* dst = (which == 0) ? q_out : k_out;
                float sc = (which == 0) ? 0.18033688f : 1.0f;  // 0.125*log2(e)
#pragma unroll
                for (int r = 0; r < 4; ++r)
                    dst[((size_t)bh * 2048 + n0 + r) * 64 + d] = f2bf(acc[i][j][r] * sc);
            }
        }
    }
}

// ---------------- proj GEMM: 256x128 block, 8 waves (2Mx4N), wave 128x32 ----
// Same template as gemm_qkv (r8-proven): 3 LDS bufs (72KB), dist-2 prefetch,
// 3 wave-uniform stage-ops/thread/tile -> vmcnt(3) boundary, 2 lockstep
// phases with setprio MFMA clusters. Grid 32x8 = 256 = exactly 1 block/CU.
// out = xout @ wproj^T + bias (fp32).
__global__ void __launch_bounds__(512, 2)
gemm_proj(const u16* __restrict__ A, const u16* __restrict__ B,
          float* __restrict__ f_out, const float* __restrict__ bias) {
    __shared__ u16 As[3][256 * 32];
    __shared__ u16 Bs[3][128 * 32];
    const int tid  = threadIdx.x;
    const int lane = tid & 63;
    const int w    = tid >> 6;
    const int wr   = w >> 2;        // 0..1
    const int wc   = w & 3;         // 0..3
    const int row0 = blockIdx.x * 256;
    const int col0 = blockIdx.y * 128;
    const int m    = lane & 15;
    const int g    = lane >> 4;

    floatx4 acc[8][2] = {};

#define STAGE_PA(buf, kelem)                                                    \
    do {                                                                        \
        _Pragma("unroll")                                                       \
        for (int i = 0; i < 2; ++i) {                                           \
            int p = tid + i * 512;                                              \
            int r = p >> 2;                                                     \
            int c = (p & 3) ^ ((r >> 1) & 3);                                   \
            async16(A + (size_t)(row0 + r) * 1024 + ((kelem) + c * 8),          \
                    (char*)&As[buf][0] + p * 16);                               \
        }                                                                       \
    } while (0)

#define STAGE_PB(buf, kelem)                                                    \
    do {                                                                        \
        int p = tid;                                                            \
        int r = p >> 2;                                                         \
        int c = (p & 3) ^ ((r >> 1) & 3);                                       \
        async16(B + (size_t)(col0 + r) * 1024 + ((kelem) + c * 8),              \
                (char*)&Bs[buf][0] + p * 16);                                   \
    } while (0)

    STAGE_PA(0, 0);  STAGE_PB(0, 0);
    STAGE_PA(1, 32); STAGE_PB(1, 32);

    int cur = 0, nx2 = 2;
    for (int kt = 0; kt < 32; ++kt) {
        if (kt < 31) asm volatile("s_waitcnt vmcnt(3)" ::: "memory");
        else         asm volatile("s_waitcnt vmcnt(0)" ::: "memory");
        __builtin_amdgcn_s_barrier();

        const u16* as = &As[cur][0];
        const u16* bs = &Bs[cur][0];
        short8 af[8], bf[2];
        // ---- phase 1: B frags + A frags 0-3, stage A(kt+2), MFMA half 1 ----
#pragma unroll
        for (int j = 0; j < 2; ++j) {
            int br = wc * 32 + j * 16 + m;
            bf[j] = *(const short8*)(bs + br * 32 + (g ^ ((br >> 1) & 3)) * 8);
        }
#pragma unroll
        for (int i = 0; i < 4; ++i) {
            int ar = wr * 128 + i * 16 + m;
            af[i] = *(const short8*)(as + ar * 32 + (g ^ ((ar >> 1) & 3)) * 8);
        }
        if (kt + 2 < 32) STAGE_PA(nx2, (kt + 2) * 32);
        __builtin_amdgcn_s_setprio(1);
#pragma unroll
        for (int i = 0; i < 4; ++i)
#pragma unroll
            for (int j = 0; j < 2; ++j)
                acc[i][j] = __builtin_amdgcn_mfma_f32_16x16x32_bf16(af[i], bf[j], acc[i][j], 0, 0, 0);
        __builtin_amdgcn_s_setprio(0);
        __builtin_amdgcn_s_barrier();
        // ---- phase 2: A frags 4-7, stage B(kt+2), MFMA half 2 ----
#pragma unroll
        for (int i = 4; i < 8; ++i) {
            int ar = wr * 128 + i * 16 + m;
            af[i] = *(const short8*)(as + ar * 32 + (g ^ ((ar >> 1) & 3)) * 8);
        }
        if (kt + 2 < 32) STAGE_PB(nx2, (kt + 2) * 32);
        __builtin_amdgcn_s_setprio(1);
#pragma unroll
        for (int i = 4; i < 8; ++i)
#pragma unroll
            for (int j = 0; j < 2; ++j)
                acc[i][j] = __builtin_amdgcn_mfma_f32_16x16x32_bf16(af[i], bf[j], acc[i][j], 0, 0, 0);
        __builtin_amdgcn_s_setprio(0);

        cur = (cur == 2) ? 0 : cur + 1;
        nx2 = (nx2 == 2) ? 0 : nx2 + 1;
    }
#undef STAGE_PA
#undef STAGE_PB

#pragma unroll
    for (int i = 0; i < 8; ++i) {
#pragma unroll
        for (int j = 0; j < 2; ++j) {
            int gr0 = row0 + wr * 128 + i * 16 + (g << 2);
            int gc  = col0 + wc * 32 + j * 16 + m;
            float bv = bias[gc];
#pragma unroll
            for (int r = 0; r < 4; ++r)
                f_out[(size_t)(gr0 + r) * 1024 + gc] = acc[i][j][r] + bv;
        }
    }
}

// ---------------- flash attention: 32 queries/wave, fixed-max softmax -------
// 1-D grid 896: bh = id&63 (XCD-local K/V), qt = id>>6 (14 tiles of 128 q).
// block 256 = 4 waves. r9: launch_bounds min-waves 3 -> 4 (LDS 32KB allows
// 4 blocks/CU = 128KB): all 896 blocks resident at t=0, removing the
// 128-block serialized tail (896 = 3.5/CU) and adding TLP for the ~20%
// stall fraction.
// V staged through LDS like K (r6); QK A-operand rows key-permuted so S^T
// regs land in 16x16x32 B-frag layout; PV at K=32 from registers; lsum via
// ones-MFMA; truncation pack; s_setprio(1) around MFMA clusters (T5).
__global__ void __launch_bounds__(256, 4)
flash_attn(const u16* __restrict__ Qg, const u16* __restrict__ Kg,
           const u16* __restrict__ Vf, u16* __restrict__ xout) {
    __shared__ u16 Ks[2][64 * 64];
    __shared__ u16 Vs[2][8 * 512];
    const int lane = threadIdx.x & 63;
    const int w    = threadIdx.x >> 6;
    const int bh   = blockIdx.x & 63;
    const int qt   = blockIdx.x >> 6;
    const int q0   = 256 + qt * 128 + w * 32;
    const size_t kvbase = (size_t)bh * 2048 * 64;

    const int m = lane & 15;
    const int g = lane >> 4;

    // Q frags (B-operand of 16x16x32): query q0+qs*16+m, k=g*8+j
    short8 qf[2][2];
#pragma unroll
    for (int qs = 0; qs < 2; ++qs) {
        const u16* p = Qg + kvbase + (size_t)(q0 + qs * 16 + m) * 64 + g * 8;
        qf[qs][0] = *(const short8*)(p);
        qf[qs][1] = *(const short8*)(p + 32);
    }

    // V global base: frag-group j = b32*4+i of tile kt lives at
    // vg + (kt*8 + j)*512 + lane*8  (contiguous 1KB per group)
    const u16* vg = Vf + (size_t)bh * 131072;

    // K staging: slot p holds row r=p>>3, chunk-pos p&7 = data chunk ^ f(r),
    // f(r) = ((r>>3)&1)*4 + (r&3)
    const int p0 = w * 64 + lane;
    const int tid = threadIdx.x;
#define STAGE_KV(buf, kt)                                                       \
    {                                                                           \
        _Pragma("unroll")                                                       \
        for (int i = 0; i < 2; ++i) {                                           \
            int p = i * 256 + p0;                                               \
            int r = p >> 3;                                                     \
            int c = (p & 7) ^ ((((r >> 3) & 1) << 2) | (r & 3));                \
            async16(Kg + kvbase + (size_t)((kt) * 64 + r) * 64 + c * 8,         \
                    (char*)&Ks[buf][0] + p * 16);                               \
        }                                                                       \
        _Pragma("unroll")                                                       \
        for (int i = 0; i < 2; ++i) {                                           \
            int p = i * 256 + tid;                                              \
            async16(vg + (size_t)((kt) * 8 + (p >> 6)) * 512 + (p & 63) * 8,    \
                    (char*)&Vs[buf][0] + p * 16);                               \
        }                                                                       \
    }

    STAGE_KV(0, 0);

    // hoisted constants: QK acc init quad (MFMA C-operand, read-only) and
    // all-ones bf16 A-frag for the lsum MFMA
    const floatx4 ZROW = {-32.f, -32.f, -32.f, -32.f};
    short8 ones1;
#pragma unroll
    for (int i = 0; i < 8; ++i) ones1[i] = (short)0x3F80;

    floatx4 lacc[2] = {};
    floatx4 o[2][4] = {};

    const int fm = ((m >> 2) & 1) * 4 + (m & 3);   // = f(r) for this lane's rows

    for (int kt = 0; kt < 32; ++kt) {
        __syncthreads();
        if (kt + 1 < 32) STAGE_KV((kt + 1) & 1, kt + 1);

        const u16* kbuf = &Ks[kt & 1][0];
        const u16* vbuf = &Vs[kt & 1][0];
#pragma unroll
        for (int b32 = 0; b32 < 2; ++b32) {
            // V A-frags for this 32-key block, from LDS (1KB contiguous/frag)
            short8 vfr[4];
#pragma unroll
            for (int i = 0; i < 4; ++i)
                vfr[i] = *(const short8*)(vbuf + ((b32 * 4 + i) * 64 + lane) * 8);

            // S^T tiles: A row = key b32*32 + (m>>2)*8 + t*4 + (m&3)
            floatx4 sT[2][2];
#pragma unroll
            for (int t = 0; t < 2; ++t) {
                int r = b32 * 32 + (m >> 2) * 8 + t * 4 + (m & 3);
                short8 k0 = *(const short8*)(kbuf + r * 64 + ((g)     ^ fm) * 8);
                short8 k1 = *(const short8*)(kbuf + r * 64 + ((4 + g) ^ fm) * 8);
                __builtin_amdgcn_s_setprio(1);
#pragma unroll
                for (int qs = 0; qs < 2; ++qs) {
                    floatx4 z = __builtin_amdgcn_mfma_f32_16x16x32_bf16(k0, qf[qs][0], ZROW, 0, 0, 0);
                    sT[qs][t] = __builtin_amdgcn_mfma_f32_16x16x32_bf16(k1, qf[qs][1], z, 0, 0, 0);
                }
                __builtin_amdgcn_s_setprio(0);
            }

            // exp2, pack P^T (16x16x32 B-frag: j -> key g*8+j), PV at K=32
#pragma unroll
            for (int qs = 0; qs < 2; ++qs) {
                float p[8];
#pragma unroll
                for (int t = 0; t < 2; ++t)
#pragma unroll
                    for (int r = 0; r < 4; ++r)
                        p[t * 4 + r] = __builtin_amdgcn_exp2f(sT[qs][t][r]);
                union { int i4[4]; short8 s8; } u;
                u.i4[0] = pk2t(p[0], p[1]);
                u.i4[1] = pk2t(p[2], p[3]);
                u.i4[2] = pk2t(p[4], p[5]);
                u.i4[3] = pk2t(p[6], p[7]);
                __builtin_amdgcn_s_setprio(1);
#pragma unroll
                for (int i = 0; i < 4; ++i)
                    o[qs][i] = __builtin_amdgcn_mfma_f32_16x16x32_bf16(vfr[i], u.s8, o[qs][i], 0, 0, 0);
                // row-sum of P via ones-MFMA: lacc[qs][*] = sum_k P[q][k]
                lacc[qs] = __builtin_amdgcn_mfma_f32_16x16x32_bf16(ones1, u.s8, lacc[qs], 0, 0, 0);
                __builtin_amdgcn_s_setprio(0);
            }
        }
    }

    const int b = bh >> 4, h = bh & 15;
#pragma unroll
    for (int qs = 0; qs < 2; ++qs) {
        // every lane already holds the full row sum for its query (col=lane&15)
        const float inv = 1.f / lacc[qs][0];

        // epilogue: O^T C-layout: col=q=m, row=d=i*16+g*4+r
        const int n = q0 + qs * 16 + m;
        u16* dst = xout + (size_t)(b * 2048 + n) * 1024 + h * 64 + (g << 2);
#pragma unroll
        for (int i = 0; i < 4; ++i) {
            union { int i2[2]; u16x4 s4; } u;
            u.i2[0] = pk_bf16(o[qs][i][0] * inv, o[qs][i][1] * inv);
            u.i2[1] = pk_bf16(o[qs][i][2] * inv, o[qs][i][3] * inv);
            *reinterpret_cast<u16x4*>(dst + i * 16) = u.s4;
        }
    }
#undef STAGE_KV
}

// ---------------- launch ----------------
extern "C" void kernel_launch(void* const* d_in, const int* in_sizes, int n_in,
                              void* d_out, int out_size, void* d_ws, size_t ws_size,
                              hipStream_t stream) {
    const float* x      = (const float*)d_in[0];
    const float* qkv_w  = (const float*)d_in[1];
    const float* proj_w = (const float*)d_in[2];
    const float* proj_b = (const float*)d_in[3];

    char* ws = (char*)d_ws;
    u16* xb    = (u16*)(ws);                       // 16 MB
    u16* xout  = (u16*)(ws + ((size_t)16 << 20));  // 16 MB
    u16* wqkv  = (u16*)(ws + ((size_t)32 << 20));  //  6 MB
    u16* wproj = (u16*)(ws + ((size_t)38 << 20));  //  2 MB
    u16* Qb    = (u16*)(ws + ((size_t)40 << 20));  // 16 MB [bh][n][64] (pre-scaled)
    u16* Kb    = (u16*)(ws + ((size_t)56 << 20));  // 16 MB [bh][n][64]
    u16* Vfb   = (u16*)(ws + ((size_t)72 << 20));  // 16 MB lane-tiled for K=32 PV

    cvt_all<<<12288, 256, 0, stream>>>(x, xb, xout, qkv_w, wqkv, proj_w, wproj);
    gemm_qkv<<<dim3(32, 16), 512, 0, stream>>>(xb, wqkv, Qb, Kb, Vfb);
    flash_attn<<<896, 256, 0, stream>>>(Qb, Kb, Vfb, xout);
    gemm_proj<<<dim3(32, 8), 512, 0, stream>>>(xout, wproj, (float*)d_out, proj_b);
}

// Round 10
// 238.884 us; speedup vs baseline: 1.0710x; 1.0360x over previous
//
#include <hip/hip_runtime.h>
#include <stdint.h>

typedef unsigned short u16;
typedef __attribute__((ext_vector_type(4))) short short4v;
typedef __attribute__((ext_vector_type(8))) short short8;
typedef __attribute__((ext_vector_type(4))) float floatx4;
typedef __attribute__((ext_vector_type(4))) unsigned short u16x4;

typedef __attribute__((address_space(1))) const void* gas_ptr;
typedef __attribute__((address_space(3))) void* las_ptr;

__device__ __forceinline__ void async16(const void* g, void* l) {
    __builtin_amdgcn_global_load_lds((gas_ptr)g, (las_ptr)l, 16, 0, 0);
}

__device__ __forceinline__ u16 f2bf(float f) {
    union { float f; unsigned int u; } v; v.f = f;
    unsigned int r = v.u + 0x7fffu + ((v.u >> 16) & 1u);
    return (u16)(r >> 16);
}

__device__ __forceinline__ int pk_bf16(float a, float b) {
    return (int)((unsigned int)f2bf(a) | ((unsigned int)f2bf(b) << 16));
}

// truncation pack: high halves of {b,a}, b in high 16. P feeds BOTH the PV
// numerator and the ones-MFMA denominator, so the truncation bias is
// common-mode and cancels in the softmax ratio. 1 VALU op vs 3.
// (v_cvt_pk_bf16_f32 asm FAILED numerics in r1 — do not reintroduce.)
__device__ __forceinline__ int pk2t(float a, float b) {
    union { float f; unsigned int u; } ua, ub;
    ua.f = a; ub.f = b;
    return (int)__builtin_amdgcn_perm(ub.u, ua.u, 0x07060302u);
}

// ---------------- merged converts (one launch instead of three) ------------
__global__ void cvt_all(const float* __restrict__ x, u16* __restrict__ xb,
                        u16* __restrict__ xout,
                        const float* __restrict__ qkv_w, u16* __restrict__ wqkv,
                        const float* __restrict__ proj_w, u16* __restrict__ wproj) {
    int b = blockIdx.x;
    const float* src;
    u16* dst;
    int i;
    if (b < 8192)       { src = x;      dst = xb;    i = b * 256 + threadIdx.x; }
    else if (b < 11264) { src = qkv_w;  dst = wqkv;  i = (b - 8192) * 256 + threadIdx.x; }
    else                { src = proj_w; dst = wproj; i = (b - 11264) * 256 + threadIdx.x; }
    float4 f = reinterpret_cast<const float4*>(src)[i];
    u16x4 o;
    o.x = f2bf(f.x); o.y = f2bf(f.y); o.z = f2bf(f.z); o.w = f2bf(f.w);
    reinterpret_cast<u16x4*>(dst)[i] = o;
    if (b < 8192) {
        int m = (i * 4) >> 10;
        if ((m & 2047) < 256) reinterpret_cast<u16x4*>(xout)[i] = o;
    }
}

// ---------------- QKV GEMM: 256x192 block, 8 waves (2Mx4N), wave 128x48 ----
// (r8 structure, kept verbatim.)
__global__ void __launch_bounds__(512, 2)
gemm_qkv(const u16* __restrict__ A, const u16* __restrict__ B,
         u16* __restrict__ q_out, u16* __restrict__ k_out, u16* __restrict__ vt_out) {
    __shared__ u16 As[3][256 * 32];
    __shared__ u16 Bs[3][192 * 32];
    const int tid  = threadIdx.x;
    const int lane = tid & 63;
    const int w    = tid >> 6;
    const int wr   = w >> 2;
    const int wc   = w & 3;
    const int row0 = blockIdx.x * 256;
    const int col0 = blockIdx.y * 192;
    const int m    = lane & 15;
    const int g    = lane >> 4;

    floatx4 acc[8][3] = {};

#define STAGE_A8(buf, kelem)                                                    \
    do {                                                                        \
        _Pragma("unroll")                                                       \
        for (int i = 0; i < 2; ++i) {                                           \
            int p = tid + i * 512;                                              \
            int r = p >> 2;                                                     \
            int c = (p & 3) ^ ((r >> 1) & 3);                                   \
            async16(A + (size_t)(row0 + r) * 1024 + ((kelem) + c * 8),          \
                    (char*)&As[buf][0] + p * 16);                               \
        }                                                                       \
    } while (0)

#define STAGE_B8(buf, kelem)                                                    \
    do {                                                                        \
        _Pragma("unroll")                                                       \
        for (int i = 0; i < 2; ++i) {                                           \
            int p = (i == 0) ? tid : (tid + 256);                               \
            int r = p >> 2;                                                     \
            int c = (p & 3) ^ ((r >> 1) & 3);                                   \
            async16(B + (size_t)(col0 + r) * 1024 + ((kelem) + c * 8),          \
                    (char*)&Bs[buf][0] + p * 16);                               \
        }                                                                       \
    } while (0)

    STAGE_A8(0, 0);  STAGE_B8(0, 0);
    STAGE_A8(1, 32); STAGE_B8(1, 32);

    int cur = 0, nx2 = 2;
    for (int kt = 0; kt < 32; ++kt) {
        if (kt < 31) asm volatile("s_waitcnt vmcnt(4)" ::: "memory");
        else         asm volatile("s_waitcnt vmcnt(0)" ::: "memory");
        __builtin_amdgcn_s_barrier();

        const u16* as = &As[cur][0];
        const u16* bs = &Bs[cur][0];
        short8 af[8], bf[3];
#pragma unroll
        for (int j = 0; j < 3; ++j) {
            int br = wc * 48 + j * 16 + m;
            bf[j] = *(const short8*)(bs + br * 32 + (g ^ ((br >> 1) & 3)) * 8);
        }
#pragma unroll
        for (int i = 0; i < 4; ++i) {
            int ar = wr * 128 + i * 16 + m;
            af[i] = *(const short8*)(as + ar * 32 + (g ^ ((ar >> 1) & 3)) * 8);
        }
        if (kt + 2 < 32) STAGE_A8(nx2, (kt + 2) * 32);
        __builtin_amdgcn_s_setprio(1);
#pragma unroll
        for (int i = 0; i < 4; ++i)
#pragma unroll
            for (int j = 0; j < 3; ++j)
                acc[i][j] = __builtin_amdgcn_mfma_f32_16x16x32_bf16(af[i], bf[j], acc[i][j], 0, 0, 0);
        __builtin_amdgcn_s_setprio(0);
        __builtin_amdgcn_s_barrier();
#pragma unroll
        for (int i = 4; i < 8; ++i) {
            int ar = wr * 128 + i * 16 + m;
            af[i] = *(const short8*)(as + ar * 32 + (g ^ ((ar >> 1) & 3)) * 8);
        }
        if (kt + 2 < 32) STAGE_B8(nx2, (kt + 2) * 32);
        __builtin_amdgcn_s_setprio(1);
#pragma unroll
        for (int i = 4; i < 8; ++i)
#pragma unroll
            for (int j = 0; j < 3; ++j)
                acc[i][j] = __builtin_amdgcn_mfma_f32_16x16x32_bf16(af[i], bf[j], acc[i][j], 0, 0, 0);
        __builtin_amdgcn_s_setprio(0);

        cur = (cur == 2) ? 0 : cur + 1;
        nx2 = (nx2 == 2) ? 0 : nx2 + 1;
    }
#undef STAGE_A8
#undef STAGE_B8

#pragma unroll
    for (int i = 0; i < 8; ++i) {
#pragma unroll
        for (int j = 0; j < 3; ++j) {
            int gr0 = row0 + wr * 128 + i * 16 + (g << 2);
            int gc  = col0 + wc * 48 + j * 16 + m;
            int which = gc >> 10;
            int cl = gc & 1023;
            int h = cl >> 6, d = cl & 63;
            int b = gr0 >> 11, n0 = gr0 & 2047;
            int bh = b * 16 + h;
            if (which == 2) {
                u16x4 pk;
                pk.x = f2bf(acc[i][j][0]); pk.y = f2bf(acc[i][j][1]);
                pk.z = f2bf(acc[i][j][2]); pk.w = f2bf(acc[i][j][3]);
                size_t off = (size_t)bh * 131072
                           + (((size_t)(n0 >> 5) * 4 + (d >> 4)) * 64
                              + ((n0 >> 3) & 3) * 16 + (d & 15)) * 8 + (n0 & 4);
                *reinterpret_cast<u16x4*>(vt_out + off) = pk;
            } else {
                u16* dst = (which == 0) ? q_out : k_out;
                float sc = (which == 0) ? 0.18033688f : 1.0f;  // 0.125*log2(e)
#pragma unroll
                for (int r = 0; r < 4; ++r)
                    dst[((size_t)bh * 2048 + n0 + r) * 64 + d] = f2bf(acc[i][j][r] * sc);
            }
        }
    }
}

// ---------------- proj GEMM: 256x128 block, 8 waves, wave 128x32 (r9) ------
__global__ void __launch_bounds__(512, 2)
gemm_proj(const u16* __restrict__ A, const u16* __restrict__ B,
          float* __restrict__ f_out, const float* __restrict__ bias) {
    __shared__ u16 As[3][256 * 32];
    __shared__ u16 Bs[3][128 * 32];
    const int tid  = threadIdx.x;
    const int lane = tid & 63;
    const int w    = tid >> 6;
    const int wr   = w >> 2;
    const int wc   = w & 3;
    const int row0 = blockIdx.x * 256;
    const int col0 = blockIdx.y * 128;
    const int m    = lane & 15;
    const int g    = lane >> 4;

    floatx4 acc[8][2] = {};

#define STAGE_PA(buf, kelem)                                                    \
    do {                                                                        \
        _Pragma("unroll")                                                       \
        for (int i = 0; i < 2; ++i) {                                           \
            int p = tid + i * 512;                                              \
            int r = p >> 2;                                                     \
            int c = (p & 3) ^ ((r >> 1) & 3);                                   \
            async16(A + (size_t)(row0 + r) * 1024 + ((kelem) + c * 8),          \
                    (char*)&As[buf][0] + p * 16);                               \
        }                                                                       \
    } while (0)

#define STAGE_PB(buf, kelem)                                                    \
    do {                                                                        \
        int p = tid;                                                            \
        int r = p >> 2;                                                         \
        int c = (p & 3) ^ ((r >> 1) & 3);                                       \
        async16(B + (size_t)(col0 + r) * 1024 + ((kelem) + c * 8),              \
                (char*)&Bs[buf][0] + p * 16);                                   \
    } while (0)

    STAGE_PA(0, 0);  STAGE_PB(0, 0);
    STAGE_PA(1, 32); STAGE_PB(1, 32);

    int cur = 0, nx2 = 2;
    for (int kt = 0; kt < 32; ++kt) {
        if (kt < 31) asm volatile("s_waitcnt vmcnt(3)" ::: "memory");
        else         asm volatile("s_waitcnt vmcnt(0)" ::: "memory");
        __builtin_amdgcn_s_barrier();

        const u16* as = &As[cur][0];
        const u16* bs = &Bs[cur][0];
        short8 af[8], bf[2];
#pragma unroll
        for (int j = 0; j < 2; ++j) {
            int br = wc * 32 + j * 16 + m;
            bf[j] = *(const short8*)(bs + br * 32 + (g ^ ((br >> 1) & 3)) * 8);
        }
#pragma unroll
        for (int i = 0; i < 4; ++i) {
            int ar = wr * 128 + i * 16 + m;
            af[i] = *(const short8*)(as + ar * 32 + (g ^ ((ar >> 1) & 3)) * 8);
        }
        if (kt + 2 < 32) STAGE_PA(nx2, (kt + 2) * 32);
        __builtin_amdgcn_s_setprio(1);
#pragma unroll
        for (int i = 0; i < 4; ++i)
#pragma unroll
            for (int j = 0; j < 2; ++j)
                acc[i][j] = __builtin_amdgcn_mfma_f32_16x16x32_bf16(af[i], bf[j], acc[i][j], 0, 0, 0);
        __builtin_amdgcn_s_setprio(0);
        __builtin_amdgcn_s_barrier();
#pragma unroll
        for (int i = 4; i < 8; ++i) {
            int ar = wr * 128 + i * 16 + m;
            af[i] = *(const short8*)(as + ar * 32 + (g ^ ((ar >> 1) & 3)) * 8);
        }
        if (kt + 2 < 32) STAGE_PB(nx2, (kt + 2) * 32);
        __builtin_amdgcn_s_setprio(1);
#pragma unroll
        for (int i = 4; i < 8; ++i)
#pragma unroll
            for (int j = 0; j < 2; ++j)
                acc[i][j] = __builtin_amdgcn_mfma_f32_16x16x32_bf16(af[i], bf[j], acc[i][j], 0, 0, 0);
        __builtin_amdgcn_s_setprio(0);

        cur = (cur == 2) ? 0 : cur + 1;
        nx2 = (nx2 == 2) ? 0 : nx2 + 1;
    }
#undef STAGE_PA
#undef STAGE_PB

#pragma unroll
    for (int i = 0; i < 8; ++i) {
#pragma unroll
        for (int j = 0; j < 2; ++j) {
            int gr0 = row0 + wr * 128 + i * 16 + (g << 2);
            int gc  = col0 + wc * 32 + j * 16 + m;
            float bv = bias[gc];
#pragma unroll
            for (int r = 0; r < 4; ++r)
                f_out[(size_t)(gr0 + r) * 1024 + gc] = acc[i][j][r] + bv;
        }
    }
}

// ---------------- flash attention: 64 queries/wave, fixed-max softmax -------
// r10: K/V LDS frag addresses depend only on lane, NOT the wave — all 4
// waves read byte-identical LDS data. r9 arithmetic: 8.5 waves x 16KB reads
// per wave-kt / 1506cyc wall = 90 B/cyc = the measured per-CU ds_read_b128
// ceiling (m134) -> flash was LDS-READ-PORT-bound. Fix: 64 queries/wave
// (4 qs-sets sharing each K/V read) -> total LDS reads halve, MFMA/read 2x.
// Grid 448 = 64 bh x 7 qtiles (1792 = 7*256 q/block). ~215 VGPR -> 2
// waves/SIMD (launch_bounds(256,2)), LDS 32KB -> 2 blocks/CU.
// Everything else verbatim from r9: staging, frag layouts, lsum ones-MFMA,
// truncation pack, setprio clusters, epilogue formula.
__global__ void __launch_bounds__(256, 2)
flash_attn(const u16* __restrict__ Qg, const u16* __restrict__ Kg,
           const u16* __restrict__ Vf, u16* __restrict__ xout) {
    __shared__ u16 Ks[2][64 * 64];
    __shared__ u16 Vs[2][8 * 512];
    const int lane = threadIdx.x & 63;
    const int w    = threadIdx.x >> 6;
    const int bh   = blockIdx.x & 63;
    const int qt   = blockIdx.x >> 6;
    const int q0   = 256 + qt * 256 + w * 64;
    const size_t kvbase = (size_t)bh * 2048 * 64;

    const int m = lane & 15;
    const int g = lane >> 4;

    // Q frags (B-operand of 16x16x32): query q0+qs*16+m, k=g*8+j
    short8 qf[4][2];
#pragma unroll
    for (int qs = 0; qs < 4; ++qs) {
        const u16* p = Qg + kvbase + (size_t)(q0 + qs * 16 + m) * 64 + g * 8;
        qf[qs][0] = *(const short8*)(p);
        qf[qs][1] = *(const short8*)(p + 32);
    }

    // V global base: frag-group j = b32*4+i of tile kt lives at
    // vg + (kt*8 + j)*512 + lane*8  (contiguous 1KB per group)
    const u16* vg = Vf + (size_t)bh * 131072;

    // K staging: slot p holds row r=p>>3, chunk-pos p&7 = data chunk ^ f(r),
    // f(r) = ((r>>3)&1)*4 + (r&3)
    const int p0 = w * 64 + lane;
    const int tid = threadIdx.x;
#define STAGE_KV(buf, kt)                                                       \
    {                                                                           \
        _Pragma("unroll")                                                       \
        for (int i = 0; i < 2; ++i) {                                           \
            int p = i * 256 + p0;                                               \
            int r = p >> 3;                                                     \
            int c = (p & 7) ^ ((((r >> 3) & 1) << 2) | (r & 3));                \
            async16(Kg + kvbase + (size_t)((kt) * 64 + r) * 64 + c * 8,         \
                    (char*)&Ks[buf][0] + p * 16);                               \
        }                                                                       \
        _Pragma("unroll")                                                       \
        for (int i = 0; i < 2; ++i) {                                           \
            int p = i * 256 + tid;                                              \
            async16(vg + (size_t)((kt) * 8 + (p >> 6)) * 512 + (p & 63) * 8,    \
                    (char*)&Vs[buf][0] + p * 16);                               \
        }                                                                       \
    }

    STAGE_KV(0, 0);

    // hoisted constants: QK acc init quad (MFMA C-operand, read-only) and
    // all-ones bf16 A-frag for the lsum MFMA
    const floatx4 ZROW = {-32.f, -32.f, -32.f, -32.f};
    short8 ones1;
#pragma unroll
    for (int i = 0; i < 8; ++i) ones1[i] = (short)0x3F80;

    floatx4 lacc[4] = {};
    floatx4 o[4][4] = {};

    const int fm = ((m >> 2) & 1) * 4 + (m & 3);   // = f(r) for this lane's rows

    for (int kt = 0; kt < 32; ++kt) {
        __syncthreads();
        if (kt + 1 < 32) STAGE_KV((kt + 1) & 1, kt + 1);

        const u16* kbuf = &Ks[kt & 1][0];
        const u16* vbuf = &Vs[kt & 1][0];
#pragma unroll
        for (int b32 = 0; b32 < 2; ++b32) {
            // V A-frags for this 32-key block, from LDS (1KB contiguous/frag)
            short8 vfr[4];
#pragma unroll
            for (int i = 0; i < 4; ++i)
                vfr[i] = *(const short8*)(vbuf + ((b32 * 4 + i) * 64 + lane) * 8);

            // S^T tiles: A row = key b32*32 + (m>>2)*8 + t*4 + (m&3)
            floatx4 sT[4][2];
#pragma unroll
            for (int t = 0; t < 2; ++t) {
                int r = b32 * 32 + (m >> 2) * 8 + t * 4 + (m & 3);
                short8 k0 = *(const short8*)(kbuf + r * 64 + ((g)     ^ fm) * 8);
                short8 k1 = *(const short8*)(kbuf + r * 64 + ((4 + g) ^ fm) * 8);
                __builtin_amdgcn_s_setprio(1);
#pragma unroll
                for (int qs = 0; qs < 4; ++qs) {
                    floatx4 z = __builtin_amdgcn_mfma_f32_16x16x32_bf16(k0, qf[qs][0], ZROW, 0, 0, 0);
                    sT[qs][t] = __builtin_amdgcn_mfma_f32_16x16x32_bf16(k1, qf[qs][1], z, 0, 0, 0);
                }
                __builtin_amdgcn_s_setprio(0);
            }

            // exp2, pack P^T (16x16x32 B-frag: j -> key g*8+j), PV at K=32
#pragma unroll
            for (int qs = 0; qs < 4; ++qs) {
                float p[8];
#pragma unroll
                for (int t = 0; t < 2; ++t)
#pragma unroll
                    for (int r = 0; r < 4; ++r)
                        p[t * 4 + r] = __builtin_amdgcn_exp2f(sT[qs][t][r]);
                union { int i4[4]; short8 s8; } u;
                u.i4[0] = pk2t(p[0], p[1]);
                u.i4[1] = pk2t(p[2], p[3]);
                u.i4[2] = pk2t(p[4], p[5]);
                u.i4[3] = pk2t(p[6], p[7]);
                __builtin_amdgcn_s_setprio(1);
#pragma unroll
                for (int i = 0; i < 4; ++i)
                    o[qs][i] = __builtin_amdgcn_mfma_f32_16x16x32_bf16(vfr[i], u.s8, o[qs][i], 0, 0, 0);
                // row-sum of P via ones-MFMA: lacc[qs][*] = sum_k P[q][k]
                lacc[qs] = __builtin_amdgcn_mfma_f32_16x16x32_bf16(ones1, u.s8, lacc[qs], 0, 0, 0);
                __builtin_amdgcn_s_setprio(0);
            }
        }
    }

    const int b = bh >> 4, h = bh & 15;
#pragma unroll
    for (int qs = 0; qs < 4; ++qs) {
        // every lane already holds the full row sum for its query (col=lane&15)
        const float inv = 1.f / lacc[qs][0];

        // epilogue: O^T C-layout: col=q=m, row=d=i*16+g*4+r
        const int n = q0 + qs * 16 + m;
        u16* dst = xout + (size_t)(b * 2048 + n) * 1024 + h * 64 + (g << 2);
#pragma unroll
        for (int i = 0; i < 4; ++i) {
            union { int i2[2]; u16x4 s4; } u;
            u.i2[0] = pk_bf16(o[qs][i][0] * inv, o[qs][i][1] * inv);
            u.i2[1] = pk_bf16(o[qs][i][2] * inv, o[qs][i][3] * inv);
            *reinterpret_cast<u16x4*>(dst + i * 16) = u.s4;
        }
    }
#undef STAGE_KV
}

// ---------------- launch ----------------
extern "C" void kernel_launch(void* const* d_in, const int* in_sizes, int n_in,
                              void* d_out, int out_size, void* d_ws, size_t ws_size,
                              hipStream_t stream) {
    const float* x      = (const float*)d_in[0];
    const float* qkv_w  = (const float*)d_in[1];
    const float* proj_w = (const float*)d_in[2];
    const float* proj_b = (const float*)d_in[3];

    char* ws = (char*)d_ws;
    u16* xb    = (u16*)(ws);                       // 16 MB
    u16* xout  = (u16*)(ws + ((size_t)16 << 20));  // 16 MB
    u16* wqkv  = (u16*)(ws + ((size_t)32 << 20));  //  6 MB
    u16* wproj = (u16*)(ws + ((size_t)38 << 20));  //  2 MB
    u16* Qb    = (u16*)(ws + ((size_t)40 << 20));  // 16 MB [bh][n][64] (pre-scaled)
    u16* Kb    = (u16*)(ws + ((size_t)56 << 20));  // 16 MB [bh][n][64]
    u16* Vfb   = (u16*)(ws + ((size_t)72 << 20));  // 16 MB lane-tiled for K=32 PV

    cvt_all<<<12288, 256, 0, stream>>>(x, xb, xout, qkv_w, wqkv, proj_w, wproj);
    gemm_qkv<<<dim3(32, 16), 512, 0, stream>>>(xb, wqkv, Qb, Kb, Vfb);
    flash_attn<<<448, 256, 0, stream>>>(Qb, Kb, Vfb, xout);
    gemm_proj<<<dim3(32, 8), 512, 0, stream>>>(xout, wproj, (float*)d_out, proj_b);
}